// Round 3
// baseline (939.789 us; speedup 1.0000x reference)
//
#include <hip/hip_runtime.h>
#include <math.h>

#define DIM 64
#define NW 4            // waves per block
#define NPB 4           // nodes per wave per iteration (node-side kernels)

__device__ __forceinline__ float waveReduceSum(float v) {
    #pragma unroll
    for (int off = 1; off < 64; off <<= 1)
        v += __shfl_xor(v, off, 64);
    return v;
}

// ---------------- Kernel A: LayerNorm + QKV projection ----------------
__global__ __launch_bounds__(256) void qkv_kernel(
    const float* __restrict__ node_feat,
    const float* __restrict__ ln_g, const float* __restrict__ ln_b,
    const float* __restrict__ qkv_w, const float* __restrict__ qkv_b,
    float* __restrict__ q, float* __restrict__ k, float* __restrict__ v,
    int N)
{
    __shared__ float  wlds[64 * 192];        // [d][j_permuted]  48 KB
    __shared__ float4 xs[NW][NPB][16];
    const int wave = threadIdx.x >> 6, lane = threadIdx.x & 63;

    for (int idx = threadIdx.x; idx < 64 * 192; idx += 256) {
        int d = idx / 192, j = idx - d * 192;
        int jj = j & 63, sec = j >> 6;                 // sec: 0=q 1=k 2=v
        int c = 12 * (jj >> 2) + (jj & 3) + 4 * sec;   // h*12 + t + 4*sec
        wlds[idx] = qkv_w[d * 192 + c];
    }
    const int c0 = 12 * (lane >> 2) + (lane & 3);
    const float b0 = qkv_b[c0], b1 = qkv_b[c0 + 4], b2 = qkv_b[c0 + 8];
    const float gg = ln_g[lane], bb = ln_b[lane];
    __syncthreads();

    const int nstride = gridDim.x * NW * NPB;
    for (int n0 = (blockIdx.x * NW + wave) * NPB; n0 < N; n0 += nstride) {
        const int cnt = min(NPB, N - n0);
        float acc0[NPB], acc1[NPB], acc2[NPB];
        #pragma unroll
        for (int i = 0; i < NPB; ++i) {
            acc0[i] = b0; acc1[i] = b1; acc2[i] = b2;
            if (i < cnt) {
                float nf = node_feat[(size_t)(n0 + i) * DIM + lane];
                float mu = waveReduceSum(nf) * (1.0f / 64.0f);
                float dv = nf - mu;
                float var = waveReduceSum(dv * dv) * (1.0f / 64.0f);
                float x = dv * rsqrtf(var + 1e-5f) * gg + bb;
                ((float*)&xs[wave][i][0])[lane] = x;   // same-wave LDS, in-order
            }
        }
        #pragma unroll 4
        for (int d4 = 0; d4 < 16; ++d4) {
            float4 xv[NPB];
            #pragma unroll
            for (int i = 0; i < NPB; ++i) xv[i] = xs[wave][i][d4];
            #pragma unroll
            for (int u = 0; u < 4; ++u) {
                int d = d4 * 4 + u;
                float w0 = wlds[d * 192 + lane];
                float w1 = wlds[d * 192 + lane + 64];
                float w2 = wlds[d * 192 + lane + 128];
                #pragma unroll
                for (int i = 0; i < NPB; ++i) {
                    float xd = (&xv[i].x)[u];
                    acc0[i] = fmaf(xd, w0, acc0[i]);
                    acc1[i] = fmaf(xd, w1, acc1[i]);
                    acc2[i] = fmaf(xd, w2, acc2[i]);
                }
            }
        }
        #pragma unroll
        for (int i = 0; i < NPB; ++i) if (i < cnt) {
            size_t off = (size_t)(n0 + i) * DIM + lane;
            q[off] = acc0[i]; k[off] = acc1[i]; v[off] = acc2[i];
        }
    }
}

// ---------------- Kernel B: input_dot ----------------
__global__ __launch_bounds__(256) void vec_kernel(
    const float* __restrict__ node_vec,
    const float* __restrict__ vec_w,
    float* __restrict__ input_dot,
    int N)
{
    __shared__ float  vlds[64 * 128];          // 32 KB
    __shared__ float4 nvs[NW][NPB][3][16];
    const int wave = threadIdx.x >> 6, lane = threadIdx.x & 63;

    for (int idx = threadIdx.x; idx < 64 * 128; idx += 256)
        vlds[idx] = vec_w[idx];
    __syncthreads();

    const int nstride = gridDim.x * NW * NPB;
    for (int n0 = (blockIdx.x * NW + wave) * NPB; n0 < N; n0 += nstride) {
        const int cnt = min(NPB, N - n0);
        float a0[NPB][3], a1[NPB][3];
        #pragma unroll
        for (int i = 0; i < NPB; ++i) {
            #pragma unroll
            for (int s = 0; s < 3; ++s) {
                a0[i][s] = 0.f; a1[i][s] = 0.f;
                if (i < cnt)
                    ((float*)&nvs[wave][i][s][0])[lane] =
                        node_vec[((size_t)(n0 + i) * 3 + s) * DIM + lane];
            }
        }
        #pragma unroll 2
        for (int d4 = 0; d4 < 16; ++d4) {
            #pragma unroll
            for (int u = 0; u < 4; ++u) {
                int d = d4 * 4 + u;
                float w0 = vlds[d * 128 + lane];
                float w1 = vlds[d * 128 + lane + 64];
                #pragma unroll
                for (int i = 0; i < NPB; ++i) {
                    #pragma unroll
                    for (int s = 0; s < 3; ++s) {
                        float nv = ((float*)&nvs[wave][i][s][d4])[u];
                        a0[i][s] = fmaf(nv, w0, a0[i][s]);
                        a1[i][s] = fmaf(nv, w1, a1[i][s]);
                    }
                }
            }
        }
        #pragma unroll
        for (int i = 0; i < NPB; ++i) if (i < cnt) {
            size_t off = (size_t)(n0 + i) * DIM + lane;
            input_dot[off] = a0[i][0] * a1[i][0] + a0[i][1] * a1[i][1]
                           + a0[i][2] * a1[i][2];
        }
    }
}

// ---------------- CSR build: histogram ----------------
__global__ __launch_bounds__(256) void hist_kernel(
    const int* __restrict__ row, int* __restrict__ cnt, int E)
{
    int i = blockIdx.x * 256 + threadIdx.x;
    if (i < E) atomicAdd(&cnt[row[i]], 1);
}

// ---------------- CSR build: single-block exclusive scan ----------------
__global__ __launch_bounds__(1024) void scan_kernel(
    const int* __restrict__ cnt, int* __restrict__ off,
    int* __restrict__ cursor, int N)
{
    __shared__ int ls[1024];
    const int t = threadIdx.x;
    const int per = (N + 1023) / 1024;
    const int s0 = t * per, s1 = min(s0 + per, N);
    int sum = 0;
    for (int i = s0; i < s1; ++i) sum += cnt[i];
    ls[t] = sum;
    __syncthreads();
    for (int d = 1; d < 1024; d <<= 1) {
        int val = (t >= d) ? ls[t - d] : 0;
        __syncthreads();
        if (t >= d) ls[t] += val;
        __syncthreads();
    }
    int run = (t > 0) ? ls[t - 1] : 0;
    for (int i = s0; i < s1; ++i) {
        off[i] = run; cursor[i] = run; run += cnt[i];
    }
    if (t == 1023) off[N] = ls[1023];
}

// ---------------- CSR build: scatter edge ids ----------------
__global__ __launch_bounds__(256) void scatter_kernel(
    const int* __restrict__ row, int* __restrict__ cursor,
    int* __restrict__ eid, int E)
{
    int i = blockIdx.x * 256 + threadIdx.x;
    if (i < E) {
        int pos = atomicAdd(&cursor[row[i]], 1);
        eid[pos] = i;
    }
}

// ---------------- Kernel C: per-node aggregation + output projection ----
// One wave per node. Loops the node's CSR edge list; no atomics. Fused
// epilogue: out = m_agg @ out_w + out_b; result = idot*out[:64]+out[64:].
__global__ __launch_bounds__(256) void agg_out_kernel(
    const float* __restrict__ q,
    const float* __restrict__ k,
    const float* __restrict__ v,
    const float* __restrict__ edge_feat,   // (E,64)
    const float* __restrict__ radial,
    const int* __restrict__ col,
    const int* __restrict__ off,
    const int* __restrict__ eid,
    const float* __restrict__ input_dot,
    const float* __restrict__ out_w,       // (64,128)
    const float* __restrict__ out_b,       // (128,)
    float* __restrict__ result,            // (N,64)
    int N)
{
    __shared__ float  olds[64 * 128];      // 32 KB
    __shared__ float4 ms[NW][16];
    const int wave = threadIdx.x >> 6, lane = threadIdx.x & 63;

    for (int idx = threadIdx.x; idx < 64 * 128; idx += 256)
        olds[idx] = out_w[idx];
    const float ob0 = out_b[lane], ob1 = out_b[lane + 64];
    __syncthreads();

    const float inv_sqrt2 = 0.70710678118654752f;
    const int wstride = gridDim.x * NW;
    for (int n = blockIdx.x * NW + wave; n < N; n += wstride) {
        const float qv = q[(size_t)n * DIM + lane];
        float acc = 0.f;
        const int start = off[n], end = off[n + 1];

        for (int j0 = start; j0 < end; j0 += 64) {
            const int m = min(64, end - j0);
            int e = 0, c = 0; float rad = 0.f;
            if (lane < m) {
                e = eid[j0 + lane];        // coalesced
                c = col[e];                // 4B gather, LLC-resident
                rad = radial[e];
            }
            int i = 0;
            for (; i + 2 <= m; i += 2) {
                int   e0 = __shfl(e, i, 64),     e1 = __shfl(e, i + 1, 64);
                int   c0 = __shfl(c, i, 64),     c1 = __shfl(c, i + 1, 64);
                float r0 = __shfl(rad, i, 64),   r1 = __shfl(rad, i + 1, 64);
                float k0 = k[(size_t)c0 * DIM + lane];
                float k1 = k[(size_t)c1 * DIM + lane];
                float v0 = v[(size_t)c0 * DIM + lane];
                float v1 = v[(size_t)c1 * DIM + lane];
                float f0 = __builtin_nontemporal_load(&edge_feat[(size_t)e0 * DIM + lane]);
                float f1 = __builtin_nontemporal_load(&edge_feat[(size_t)e1 * DIM + lane]);
                float p0 = qv * k0;
                p0 += __shfl_xor(p0, 1, 64); p0 += __shfl_xor(p0, 2, 64);
                float p1 = qv * k1;
                p1 += __shfl_xor(p1, 1, 64); p1 += __shfl_xor(p1, 2, 64);
                float g0 = 0.5f * p0 * (1.0f + erff(p0 * inv_sqrt2)) * r0;
                float g1 = 0.5f * p1 * (1.0f + erff(p1 * inv_sqrt2)) * r1;
                acc = fmaf(v0 * f0, g0, acc);
                acc = fmaf(v1 * f1, g1, acc);
            }
            for (; i < m; ++i) {
                int   e0 = __shfl(e, i, 64);
                int   c0 = __shfl(c, i, 64);
                float r0 = __shfl(rad, i, 64);
                float k0 = k[(size_t)c0 * DIM + lane];
                float v0 = v[(size_t)c0 * DIM + lane];
                float f0 = __builtin_nontemporal_load(&edge_feat[(size_t)e0 * DIM + lane]);
                float p0 = qv * k0;
                p0 += __shfl_xor(p0, 1, 64); p0 += __shfl_xor(p0, 2, 64);
                float g0 = 0.5f * p0 * (1.0f + erff(p0 * inv_sqrt2)) * r0;
                acc = fmaf(v0 * f0, g0, acc);
            }
        }

        // ---- fused output projection ----
        ((float*)&ms[wave][0])[lane] = acc;    // same-wave LDS, in-order
        float o0 = ob0, o1 = ob1;
        #pragma unroll 4
        for (int d4 = 0; d4 < 16; ++d4) {
            float4 mv = ms[wave][d4];
            #pragma unroll
            for (int u = 0; u < 4; ++u) {
                int d = d4 * 4 + u;
                float md = (&mv.x)[u];
                o0 = fmaf(md, olds[d * 128 + lane], o0);
                o1 = fmaf(md, olds[d * 128 + lane + 64], o1);
            }
        }
        size_t offr = (size_t)n * DIM + lane;
        result[offr] = input_dot[offr] * o0 + o1;
    }
}

extern "C" void kernel_launch(void* const* d_in, const int* in_sizes, int n_in,
                              void* d_out, int out_size, void* d_ws, size_t ws_size,
                              hipStream_t stream)
{
    const float* node_feat = (const float*)d_in[0];
    const float* edge_feat = (const float*)d_in[1];
    const float* node_vec  = (const float*)d_in[2];
    const float* radial    = (const float*)d_in[3];
    const float* ln_g      = (const float*)d_in[4];
    const float* ln_b      = (const float*)d_in[5];
    const float* qkv_w     = (const float*)d_in[6];
    const float* qkv_b     = (const float*)d_in[7];
    const float* vec_w     = (const float*)d_in[8];
    const float* out_w     = (const float*)d_in[9];
    const float* out_b     = (const float*)d_in[10];
    const int*   row       = (const int*)d_in[11];
    const int*   col       = (const int*)d_in[12];

    const int N = in_sizes[0] / DIM;   // 50000
    const int E = in_sizes[3];         // 1250000

    // workspace: q|k|v|idot (floats) then eid|cnt|off|cursor (ints) = ~57 MB
    float* q    = (float*)d_ws;
    float* k    = q    + (size_t)N * DIM;
    float* v    = k    + (size_t)N * DIM;
    float* idot = v    + (size_t)N * DIM;
    int* eid    = (int*)(idot + (size_t)N * DIM);
    int* cnt    = eid + E;
    int* off    = cnt + N;          // N+1 entries
    int* cursor = off + N + 1;

    const int grid_nodes = 768;
    const int eblk = (E + 255) / 256;

    hipMemsetAsync(cnt, 0, (size_t)N * sizeof(int), stream);
    qkv_kernel<<<grid_nodes, 256, 0, stream>>>(node_feat, ln_g, ln_b,
                                               qkv_w, qkv_b, q, k, v, N);
    vec_kernel<<<grid_nodes, 256, 0, stream>>>(node_vec, vec_w, idot, N);
    hist_kernel<<<eblk, 256, 0, stream>>>(row, cnt, E);
    scan_kernel<<<1, 1024, 0, stream>>>(cnt, off, cursor, N);
    scatter_kernel<<<eblk, 256, 0, stream>>>(row, cursor, eid, E);
    agg_out_kernel<<<3072, 256, 0, stream>>>(q, k, v, edge_feat, radial,
                                             col, off, eid, idot,
                                             out_w, out_b, (float*)d_out, N);
}